// Round 15
// baseline (133.075 us; speedup 1.0000x reference)
//
#include <hip/hip_runtime.h>
#include <stdint.h>

#define T_SEQ 2048
#define CDIM 1024
#define NHEAD 16
#define HS 64

typedef __bf16 bf16x8 __attribute__((ext_vector_type(8)));
typedef float f32x4 __attribute__((ext_vector_type(4)));
typedef float f32x16 __attribute__((ext_vector_type(16)));

__device__ __forceinline__ unsigned short f2bf(float f) {
  union { float f; unsigned u; } c; c.f = f;
  unsigned r = c.u + 0x7FFFu + ((c.u >> 16) & 1u);
  return (unsigned short)(r >> 16);
}

__device__ __forceinline__ void gload_lds16(const void* g, void* l) {
  __builtin_amdgcn_global_load_lds((__attribute__((address_space(1))) void*)(g),
                                   (__attribute__((address_space(3))) void*)(l),
                                   16, 0, 0);
}

// Cross-half (lane i <-> lane i^32) exchange via permlane32_swap (pure VALU).
__device__ __forceinline__ float xhalf_other(float x, int hi) {
  union { float f; unsigned u; } c; c.f = x;
  auto r = __builtin_amdgcn_permlane32_swap(c.u, c.u, false, false);
  union { unsigned u; float f; } lo_, hi_;
  lo_.u = (unsigned)r[0]; hi_.u = (unsigned)r[1];
  return hi ? lo_.f : hi_.f;
}

// Fused prepass: [0,4096) x-cvt blocks; [4096,7168) W_attn transpose tiles;
// [7168,8192) W_proj transpose tiles. One launch, concurrent execution.
__global__ __launch_bounds__(256) void k_prep(const float* __restrict__ x,
                                              unsigned short* __restrict__ xb,
                                              const float* __restrict__ Wa,
                                              unsigned short* __restrict__ Wta,
                                              const float* __restrict__ Wp,
                                              unsigned short* __restrict__ Wtp) {
  __shared__ float tile[32][33];
  const int bid = blockIdx.x;
  if (bid < 4096) {
    int i = bid * 256 + threadIdx.x;
    float4 f = reinterpret_cast<const float4*>(x)[i];
    ushort4 u;
    u.x = f2bf(f.x); u.y = f2bf(f.y); u.z = f2bf(f.z); u.w = f2bf(f.w);
    reinterpret_cast<ushort4*>(xb)[i] = u;
    return;
  }
  const float* W; unsigned short* Wt; int N, n0, k0;
  if (bid < 7168) {
    int b2 = bid - 4096; W = Wa; Wt = Wta; N = 3072;
    n0 = (b2 % 96) * 32; k0 = (b2 / 96) * 32;
  } else {
    int b2 = bid - 7168; W = Wp; Wt = Wtp; N = 1024;
    n0 = (b2 & 31) * 32; k0 = (b2 >> 5) * 32;
  }
  int c = threadIdx.x & 31, r0 = threadIdx.x >> 5;
#pragma unroll
  for (int r = r0; r < 32; r += 8) tile[r][c] = W[(size_t)(k0 + r) * N + n0 + c];
  __syncthreads();
#pragma unroll
  for (int r = r0; r < 32; r += 8) Wt[(size_t)(n0 + r) * 1024 + k0 + c] = f2bf(tile[c][r]);
}

// GEMM1: C = A[M][1024] * Bt[N][1024]^T + bias, qkv scatter epilogue in
// FRAGMENT-LINEAR layout (R13): per 64-token tile,
//   K/Q slot = kbk*2048 + dd*512 + l31*16 + hi*8 + j
//   V slot   = db*2048 + t16*512 + l31*16 + hi*8 + j
// K pre-scaled by 1/sqrt(hs)*log2e. 128x128 tile, 4 waves, BK=32.
__global__ __launch_bounds__(256) void k_gemm1(const unsigned short* __restrict__ A,
                                               const unsigned short* __restrict__ Bt,
                                               const float* __restrict__ bias,
                                               unsigned short* __restrict__ qb,
                                               unsigned short* __restrict__ kb,
                                               unsigned short* __restrict__ vb) {
  __shared__ __align__(16) unsigned short Al[128 * 32];
  __shared__ __align__(16) unsigned short Bl[128 * 32];
  const int tid = threadIdx.x;
  const int wave = tid >> 6, lane = tid & 63;
  const int m0 = blockIdx.x * 128, n0 = blockIdx.y * 128;
  const int wr = (wave >> 1) * 64, wc = (wave & 1) * 64;
  const int srow = tid >> 2, scol = (tid & 3) * 8;
  const int ka = (lane >> 4) * 8;
  f32x4 acc[4][4];
#pragma unroll
  for (int m = 0; m < 4; ++m)
#pragma unroll
    for (int n = 0; n < 4; ++n) acc[m][n] = f32x4{0.f, 0.f, 0.f, 0.f};

  for (int k0 = 0; k0 < 1024; k0 += 32) {
#pragma unroll
    for (int r = 0; r < 2; ++r) {
      gload_lds16(A + (size_t)(m0 + r * 64 + srow) * 1024 + k0 + scol,
                  (char*)Al + r * 4096 + wave * 1024);
      gload_lds16(Bt + (size_t)(n0 + r * 64 + srow) * 1024 + k0 + scol,
                  (char*)Bl + r * 4096 + wave * 1024);
    }
    __syncthreads();
    bf16x8 af[4], bfr[4];
#pragma unroll
    for (int m = 0; m < 4; ++m)
      af[m] = *(const bf16x8*)&Al[(wr + m * 16 + (lane & 15)) * 32 + ka];
#pragma unroll
    for (int n = 0; n < 4; ++n)
      bfr[n] = *(const bf16x8*)&Bl[(wc + n * 16 + (lane & 15)) * 32 + ka];
#pragma unroll
    for (int m = 0; m < 4; ++m)
#pragma unroll
      for (int n = 0; n < 4; ++n)
        acc[m][n] = __builtin_amdgcn_mfma_f32_16x16x32_bf16(af[m], bfr[n], acc[m][n], 0, 0, 0);
    __syncthreads();
  }

#pragma unroll
  for (int m = 0; m < 4; ++m)
#pragma unroll
    for (int n = 0; n < 4; ++n)
#pragma unroll
      for (int j = 0; j < 4; ++j) {
        int row = m0 + wr + m * 16 + (lane >> 4) * 4 + j;
        int col = n0 + wc + n * 16 + (lane & 15);
        float v = acc[m][n][j] + bias[col];
        int which = col >> 10;
        int h = (col >> 6) & 15;
        int d = col & 63;
        int b = row >> 11, t = row & (T_SEQ - 1);
        int bh = b * NHEAD + h;
        unsigned short bv = f2bf(which == 1 ? v * 0.18033688f : v);
        size_t tb = ((size_t)bh * 32 + (t >> 6)) * 4096;
        if (which == 2) {
          vb[tb + (d >> 5) * 2048 + ((t >> 4) & 3) * 512 + (d & 31) * 16 +
             ((t >> 3) & 1) * 8 + (t & 7)] = bv;
        } else {
          size_t a = tb + ((t >> 5) & 1) * 2048 + (d >> 4) * 512 + (t & 31) * 16 +
                     ((d >> 3) & 1) * 8 + (d & 7);
          if (which == 0) qb[a] = bv; else kb[a] = bv;
        }
      }
}

// GEMM2: out += A[4096][1024] * Bt[1024][1024]^T (+ bias from kz==0), fp32.
// K-SPLIT-2 (this round): grid (64,8,2); block kz computes K in
// [kz*512, kz*512+512) and accumulates into the pre-zeroed out[] via HW fp32
// atomic add (__hip_atomic_fetch_add, relaxed/agent -> global_atomic_add_f32).
// 1024 blocks = 4/CU co-resident (was 2/CU) and half the K-steps per block ->
// the exposed 2-barrier stalls halve and overlap. out[] zeroed by k_attn.
__global__ __launch_bounds__(256) void k_gemm2(const unsigned short* __restrict__ A,
                                               const unsigned short* __restrict__ Bt,
                                               const float* __restrict__ bias,
                                               float* __restrict__ outF) {
  __shared__ __align__(16) unsigned short Al[64 * 32];
  __shared__ __align__(16) unsigned short Bl[128 * 32];
  const int tid = threadIdx.x;
  const int wave = tid >> 6, lane = tid & 63;
  const int m0 = blockIdx.x * 64, n0 = blockIdx.y * 128;
  const int kz = blockIdx.z;
  const int wr = (wave >> 1) * 32, wc = (wave & 1) * 64;
  const int srow = tid >> 2, scol = (tid & 3) * 8;
  const int ka = (lane >> 4) * 8;
  f32x4 acc[2][4];
#pragma unroll
  for (int m = 0; m < 2; ++m)
#pragma unroll
    for (int n = 0; n < 4; ++n) acc[m][n] = f32x4{0.f, 0.f, 0.f, 0.f};

  const int kbeg = kz * 512, kend = kbeg + 512;
  for (int k0 = kbeg; k0 < kend; k0 += 32) {
    gload_lds16(A + (size_t)(m0 + srow) * 1024 + k0 + scol, (char*)Al + wave * 1024);
#pragma unroll
    for (int r = 0; r < 2; ++r)
      gload_lds16(Bt + (size_t)(n0 + r * 64 + srow) * 1024 + k0 + scol,
                  (char*)Bl + r * 4096 + wave * 1024);
    __syncthreads();
    bf16x8 af[2], bfr[4];
#pragma unroll
    for (int m = 0; m < 2; ++m)
      af[m] = *(const bf16x8*)&Al[(wr + m * 16 + (lane & 15)) * 32 + ka];
#pragma unroll
    for (int n = 0; n < 4; ++n)
      bfr[n] = *(const bf16x8*)&Bl[(wc + n * 16 + (lane & 15)) * 32 + ka];
#pragma unroll
    for (int m = 0; m < 2; ++m)
#pragma unroll
      for (int n = 0; n < 4; ++n)
        acc[m][n] = __builtin_amdgcn_mfma_f32_16x16x32_bf16(af[m], bfr[n], acc[m][n], 0, 0, 0);
    __syncthreads();
  }

#pragma unroll
  for (int m = 0; m < 2; ++m)
#pragma unroll
    for (int n = 0; n < 4; ++n)
#pragma unroll
      for (int j = 0; j < 4; ++j) {
        int row = m0 + wr + m * 16 + (lane >> 4) * 4 + j;
        int col = n0 + wc + n * 16 + (lane & 15);
        float v = acc[m][n][j] + (kz == 0 ? bias[col] : 0.f);
        __hip_atomic_fetch_add(&outF[(size_t)row * CDIM + col], v,
                               __ATOMIC_RELAXED, __HIP_MEMORY_SCOPE_AGENT);
      }
}

// Flash attention: R14 structure (KV-split-4, 32x32 lane-local softmax,
// pipelined QK, permlane reduces, defer-max, fragment-linear Q/K/V, balanced
// pairs, 4-way LDS merge twice per block) + zeroes out[] at entry for GEMM2's
// atomic K-split (16KB/block of coalesced float4 stores, hidden under this
// kernel's latency-bound execution; stream order puts it before k_gemm2).
#define MOSTR 67
__global__ __launch_bounds__(256) void k_attn(const unsigned short* __restrict__ qb,
                                              const unsigned short* __restrict__ kb,
                                              const unsigned short* __restrict__ vb,
                                              unsigned short* __restrict__ yb,
                                              float* __restrict__ outZ) {
  __shared__ float Mo[4 * 32 * MOSTR];   // 34304 B partial O^T
  __shared__ float Lml[4][2][32];        // partial m, l per q
  // rid -> (xcd, bh, pair). 8 XCDs x 4 bh x 32 pairs = 1024 blocks.
  const int rid = blockIdx.x;
  const int xcd = rid & 7, i = rid >> 3;       // i in 0..127
  const int bh = xcd * 4 + (i & 3);
  const int p = i >> 2;                        // 0..31
  const int wave = threadIdx.x >> 6;           // 0..3
  const int lane = threadIdx.x & 63;
  const int l31 = lane & 31, hi = lane >> 5;
  const unsigned short* qh = qb + (size_t)bh * T_SEQ * HS;
  const unsigned short* kh = kb + (size_t)bh * T_SEQ * HS;
  const unsigned short* vh = vb + (size_t)bh * T_SEQ * HS;
  const int b = bh >> 4, h = bh & 15;
  const int lbase = l31 * 16 + hi * 8;         // per-lane offset within a 512-slab

  // zero out[] slice for gemm2's atomic accumulation: 1024 float4 per block.
  {
    float4 z4 = make_float4(0.f, 0.f, 0.f, 0.f);
    float4* op = reinterpret_cast<float4*>(outZ) + (size_t)rid * 1024 + threadIdx.x;
#pragma unroll
    for (int e = 0; e < 4; ++e) op[e * 256] = z4;
  }

  for (int grp = 0; grp < 2; ++grp) {
    const int g = grp ? p : 63 - p;
    const int q0 = g * 32;
    const int nkt = (q0 >> 6) + 1;

    // Q B-frags (fragment-linear): col=q=l31, k(d) = dd*16 + hi*8 + {0..7}
    const size_t qbase = (size_t)(g >> 1) * 4096 + (size_t)(g & 1) * 2048;
    bf16x8 qf[4];
#pragma unroll
    for (int dd = 0; dd < 4; ++dd)
      qf[dd] = *(const bf16x8*)&qh[qbase + dd * 512 + lbase];

    f32x16 o2[2];                 // O^T acc: col=q=l31, rows d = db*32 + rowpat
#pragma unroll
    for (int db = 0; db < 2; ++db)
#pragma unroll
      for (int e = 0; e < 16; ++e) o2[db][e] = 0.f;
    float Mx = -INFINITY, Ls = 0.f;

    // prologue: K A-frags + QK of this wave's first tile (index < 32, in-bounds)
    bf16x8 kf[2][4];
#pragma unroll
    for (int kbk = 0; kbk < 2; ++kbk)
#pragma unroll
      for (int dd = 0; dd < 4; ++dd)
        kf[kbk][dd] = *(const bf16x8*)&kh[(size_t)wave * 4096 + kbk * 2048 + dd * 512 + lbase];
    f32x16 s[2];
#pragma unroll
    for (int kbk = 0; kbk < 2; ++kbk) {
      f32x16 z;
#pragma unroll
      for (int e = 0; e < 16; ++e) z[e] = 0.f;
#pragma unroll
      for (int dd = 0; dd < 4; ++dd)
        z = __builtin_amdgcn_mfma_f32_32x32x16_bf16(kf[kbk][dd], qf[dd], z, 0, 0, 0);
      s[kbk] = z;
    }

    for (int kt = wave; kt < nkt; kt += 4) {
      const int kvb = kt * 64;
      const bool more = (kt + 4 < nkt);

      // issue K loads for tile kt+4 (kf regs free: QK(kt) already computed)
      if (more) {
#pragma unroll
        for (int kbk = 0; kbk < 2; ++kbk)
#pragma unroll
          for (int dd = 0; dd < 4; ++dd)
            kf[kbk][dd] = *(const bf16x8*)&kh[(size_t)(kt + 4) * 4096 + kbk * 2048 + dd * 512 + lbase];
      }
      // issue V loads for THIS tile (consumed after softmax -> latency hidden)
      bf16x8 vf[2][4];
#pragma unroll
      for (int db = 0; db < 2; ++db)
#pragma unroll
        for (int t16 = 0; t16 < 4; ++t16)
          vf[db][t16] = *(const bf16x8*)&vh[(size_t)kt * 4096 + db * 2048 + t16 * 512 + lbase];

      // causal mask (only the group's last tile has kvb+63 > q0)
      if (kvb + 63 > q0) {
        const int qg = q0 + l31;
#pragma unroll
        for (int kbk = 0; kbk < 2; ++kbk)
#pragma unroll
          for (int r = 0; r < 16; ++r) {
            const int key = kvb + kbk * 32 + (r & 3) + 8 * (r >> 2) + 4 * hi;
            if (key > qg) s[kbk][r] = -3.0e38f;
          }
      }

      // row max: in-register tree (31 fmax) + permlane cross-half
      f32x16 tm;
#pragma unroll
      for (int e = 0; e < 16; ++e) tm[e] = fmaxf(s[0][e], s[1][e]);
      float m8[8];
#pragma unroll
      for (int e = 0; e < 8; ++e) m8[e] = fmaxf(tm[e], tm[e + 8]);
      float m4a = fmaxf(m8[0], m8[4]), m4b = fmaxf(m8[1], m8[5]);
      float m4c = fmaxf(m8[2], m8[6]), m4d = fmaxf(m8[3], m8[7]);
      float mx = fmaxf(fmaxf(m4a, m4b), fmaxf(m4c, m4d));
      mx = fmaxf(mx, xhalf_other(mx, hi));

      // defer-max (T13): skip rescale while max growth <= 8 (P <= 2^8).
      if (!__all(mx <= Mx + 8.f)) {
        const float newM = fmaxf(Mx, mx);
        const float alpha = __builtin_exp2f(Mx - newM);
        Mx = newM;
        Ls *= alpha;
#pragma unroll
        for (int db = 0; db < 2; ++db)
#pragma unroll
          for (int e = 0; e < 16; ++e) o2[db][e] *= alpha;
      }

      // p = exp2(s - Mx) in place; row sum (31 adds) + permlane cross-half
#pragma unroll
      for (int kbk = 0; kbk < 2; ++kbk)
#pragma unroll
        for (int r = 0; r < 16; ++r) s[kbk][r] = __builtin_exp2f(s[kbk][r] - Mx);
      f32x16 ts;
#pragma unroll
      for (int e = 0; e < 16; ++e) ts[e] = s[0][e] + s[1][e];
      float s8[8];
#pragma unroll
      for (int e = 0; e < 8; ++e) s8[e] = ts[e] + ts[e + 8];
      float rs = ((s8[0] + s8[1]) + (s8[2] + s8[3])) + ((s8[4] + s8[5]) + (s8[6] + s8[7]));
      rs += xhalf_other(rs, hi);
      Ls += rs;

      // pack P: W[kb][rg] = 2 words (4 bf16, rows 8rg+4hi+{0..3})
      unsigned W0[2][4], W1[2][4];
#pragma unroll
      for (int kbk = 0; kbk < 2; ++kbk)
#pragma unroll
        for (int rg = 0; rg < 4; ++rg) {
          unsigned lo, hiw;
          asm("v_cvt_pk_bf16_f32 %0, %1, %2" : "=v"(lo) : "v"(s[kbk][4 * rg + 0]), "v"(s[kbk][4 * rg + 1]));
          asm("v_cvt_pk_bf16_f32 %0, %1, %2" : "=v"(hiw) : "v"(s[kbk][4 * rg + 2]), "v"(s[kbk][4 * rg + 3]));
          W0[kbk][rg] = lo; W1[kbk][rg] = hiw;
        }

      // build PV B-frags (P^T: col=q=l31, k = t16*16 + hi*8 + {0..7}) with
      // 8 permlane32_swap: swap(W[rgA].w, W[rgB].w) -> both frag halves.
      bf16x8 pf[4];
#pragma unroll
      for (int t16 = 0; t16 < 4; ++t16) {
        const int kbk = t16 >> 1, par = t16 & 1;
        unsigned a0 = W0[kbk][2 * par], b0 = W0[kbk][2 * par + 1];
        unsigned a1 = W1[kbk][2 * par], b1 = W1[kbk][2 * par + 1];
        auto r0 = __builtin_amdgcn_permlane32_swap(a0, b0, false, false);
        auto r1 = __builtin_amdgcn_permlane32_swap(a1, b1, false, false);
        union { unsigned u[4]; bf16x8 v; } cv;
        cv.u[0] = (unsigned)r0[0]; cv.u[1] = (unsigned)r1[0];
        cv.u[2] = (unsigned)r0[1]; cv.u[3] = (unsigned)r1[1];
        pf[t16] = cv.v;
      }

      // PV: O^T[d][q] += V[d][k] * P^T[k][q]
#pragma unroll
      for (int db = 0; db < 2; ++db)
#pragma unroll
        for (int t16 = 0; t16 < 4; ++t16)
          o2[db] = __builtin_amdgcn_mfma_f32_32x32x16_bf16(vf[db][t16], pf[t16], o2[db], 0, 0, 0);

      // QK for tile kt+4 at iteration END (kf loads had softmax+PV to land).
      if (more) {
#pragma unroll
        for (int kbk = 0; kbk < 2; ++kbk) {
          f32x16 z;
#pragma unroll
          for (int e = 0; e < 16; ++e) z[e] = 0.f;
#pragma unroll
          for (int dd = 0; dd < 4; ++dd)
            z = __builtin_amdgcn_mfma_f32_32x32x16_bf16(kf[kbk][dd], qf[dd], z, 0, 0, 0);
          s[kbk] = z;
        }
      }
    }

    // ---- publish partials ----
    if (hi == 0) {
      Lml[wave][0][l31] = Mx;
      Lml[wave][1][l31] = Ls;
    }
#pragma unroll
    for (int db = 0; db < 2; ++db)
#pragma unroll
      for (int r = 0; r < 16; ++r)
        Mo[wave * 32 * MOSTR + l31 * MOSTR + db * 32 + (r & 3) + 8 * (r >> 2) + 4 * hi] = o2[db][r];
    __syncthreads();

    // ---- distributed 4-way merge + store: 256 chunks of 8 cols ----
    {
      const int c = threadIdx.x;
      const int rl = c >> 3, c0 = (c & 7) * 8;
      const float m0 = Lml[0][0][rl], m1 = Lml[1][0][rl], m2 = Lml[2][0][rl], m3 = Lml[3][0][rl];
      const float l0 = Lml[0][1][rl], l1 = Lml[1][1][rl], l2 = Lml[2][1][rl], l3 = Lml[3][1][rl];
      const float M = fmaxf(fmaxf(m0, m1), fmaxf(m2, m3));
      const float a0 = __builtin_exp2f(m0 - M);
      const float a1 = __builtin_exp2f(m1 - M);
      const float a2 = __builtin_exp2f(m2 - M);
      const float a3 = __builtin_exp2f(m3 - M);
      const float inv = 1.0f / (a0 * l0 + a1 * l1 + a2 * l2 + a3 * l3);
      const float* O0 = &Mo[rl * MOSTR + c0];
      const float* O1 = O0 + 32 * MOSTR;
      const float* O2 = O0 + 64 * MOSTR;
      const float* O3 = O0 + 96 * MOSTR;
      unsigned pk[4];
#pragma unroll
      for (int e = 0; e < 4; ++e) {
        float va = (a0 * O0[2 * e] + a1 * O1[2 * e] + a2 * O2[2 * e] + a3 * O3[2 * e]) * inv;
        float vb2 = (a0 * O0[2 * e + 1] + a1 * O1[2 * e + 1] + a2 * O2[2 * e + 1] + a3 * O3[2 * e + 1]) * inv;
        pk[e] = (unsigned)f2bf(va) | ((unsigned)f2bf(vb2) << 16);
      }
      uint4 u; u.x = pk[0]; u.y = pk[1]; u.z = pk[2]; u.w = pk[3];
      *(uint4*)&yb[(size_t)(b * T_SEQ + q0 + rl) * CDIM + h * 64 + c0] = u;
    }
    __syncthreads();  // Mo reused by next group
  }
}

extern "C" void kernel_launch(void* const* d_in, const int* in_sizes, int n_in,
                              void* d_out, int out_size, void* d_ws, size_t ws_size,
                              hipStream_t stream) {
  (void)in_sizes; (void)n_in; (void)out_size; (void)ws_size;
  const float* x      = (const float*)d_in[0];
  const float* W_attn = (const float*)d_in[1];
  const float* b_attn = (const float*)d_in[2];
  const float* W_proj = (const float*)d_in[3];
  const float* b_proj = (const float*)d_in[4];
  float* out = (float*)d_out;
  char* ws = (char*)d_ws;

  unsigned short* xb  = (unsigned short*)(ws);              //  8 MiB [4096][1024]
  unsigned short* Wta = (unsigned short*)(ws + 8388608);    //  6 MiB [3072][1024]
  unsigned short* Wtp = (unsigned short*)(ws + 14680064);   //  2 MiB [1024][1024]
  unsigned short* qbf = (unsigned short*)(ws + 16777216);   //  8 MiB fragment-linear
  unsigned short* kbf = (unsigned short*)(ws + 25165824);   //  8 MiB fragment-linear
  unsigned short* vbf = (unsigned short*)(ws + 33554432);   //  8 MiB fragment-linear
  unsigned short* ybf = (unsigned short*)(ws + 41943040);   //  8 MiB [4096][1024]

  k_prep<<<8192, 256, 0, stream>>>(x, xb, W_attn, Wta, W_proj, Wtp);
  k_gemm1<<<dim3(32, 24), 256, 0, stream>>>(xb, Wta, b_attn, qbf, kbf, vbf);
  k_attn<<<1024, 256, 0, stream>>>(qbf, kbf, vbf, ybf, out);
  k_gemm2<<<dim3(64, 8, 2), 256, 0, stream>>>(ybf, Wtp, b_proj, out);
}

// Round 16
// 110.886 us; speedup vs baseline: 1.2001x; 1.2001x over previous
//
#include <hip/hip_runtime.h>
#include <stdint.h>

#define T_SEQ 2048
#define CDIM 1024
#define NHEAD 16
#define HS 64

typedef __bf16 bf16x8 __attribute__((ext_vector_type(8)));
typedef float f32x4 __attribute__((ext_vector_type(4)));
typedef float f32x16 __attribute__((ext_vector_type(16)));

__device__ __forceinline__ unsigned short f2bf(float f) {
  union { float f; unsigned u; } c; c.f = f;
  unsigned r = c.u + 0x7FFFu + ((c.u >> 16) & 1u);
  return (unsigned short)(r >> 16);
}

__device__ __forceinline__ void gload_lds16(const void* g, void* l) {
  __builtin_amdgcn_global_load_lds((__attribute__((address_space(1))) void*)(g),
                                   (__attribute__((address_space(3))) void*)(l),
                                   16, 0, 0);
}

// Cross-half (lane i <-> lane i^32) exchange via permlane32_swap (pure VALU).
__device__ __forceinline__ float xhalf_other(float x, int hi) {
  union { float f; unsigned u; } c; c.f = x;
  auto r = __builtin_amdgcn_permlane32_swap(c.u, c.u, false, false);
  union { unsigned u; float f; } lo_, hi_;
  lo_.u = (unsigned)r[0]; hi_.u = (unsigned)r[1];
  return hi ? lo_.f : hi_.f;
}

// Fused prepass: [0,4096) x-cvt blocks; [4096,7168) W_attn transpose tiles;
// [7168,8192) W_proj transpose tiles. One launch, concurrent execution.
__global__ __launch_bounds__(256) void k_prep(const float* __restrict__ x,
                                              unsigned short* __restrict__ xb,
                                              const float* __restrict__ Wa,
                                              unsigned short* __restrict__ Wta,
                                              const float* __restrict__ Wp,
                                              unsigned short* __restrict__ Wtp) {
  __shared__ float tile[32][33];
  const int bid = blockIdx.x;
  if (bid < 4096) {
    int i = bid * 256 + threadIdx.x;
    float4 f = reinterpret_cast<const float4*>(x)[i];
    ushort4 u;
    u.x = f2bf(f.x); u.y = f2bf(f.y); u.z = f2bf(f.z); u.w = f2bf(f.w);
    reinterpret_cast<ushort4*>(xb)[i] = u;
    return;
  }
  const float* W; unsigned short* Wt; int N, n0, k0;
  if (bid < 7168) {
    int b2 = bid - 4096; W = Wa; Wt = Wta; N = 3072;
    n0 = (b2 % 96) * 32; k0 = (b2 / 96) * 32;
  } else {
    int b2 = bid - 7168; W = Wp; Wt = Wtp; N = 1024;
    n0 = (b2 & 31) * 32; k0 = (b2 >> 5) * 32;
  }
  int c = threadIdx.x & 31, r0 = threadIdx.x >> 5;
#pragma unroll
  for (int r = r0; r < 32; r += 8) tile[r][c] = W[(size_t)(k0 + r) * N + n0 + c];
  __syncthreads();
#pragma unroll
  for (int r = r0; r < 32; r += 8) Wt[(size_t)(n0 + r) * 1024 + k0 + c] = f2bf(tile[c][r]);
}

// GEMM1: C = A[M][1024] * Bt[N][1024]^T + bias, qkv scatter epilogue in
// FRAGMENT-LINEAR layout (R13): per 64-token tile,
//   K/Q slot = kbk*2048 + dd*512 + l31*16 + hi*8 + j
//   V slot   = db*2048 + t16*512 + l31*16 + hi*8 + j
// K pre-scaled by 1/sqrt(hs)*log2e. 128x128 tile, 4 waves, BK=32.
__global__ __launch_bounds__(256) void k_gemm1(const unsigned short* __restrict__ A,
                                               const unsigned short* __restrict__ Bt,
                                               const float* __restrict__ bias,
                                               unsigned short* __restrict__ qb,
                                               unsigned short* __restrict__ kb,
                                               unsigned short* __restrict__ vb) {
  __shared__ __align__(16) unsigned short Al[128 * 32];
  __shared__ __align__(16) unsigned short Bl[128 * 32];
  const int tid = threadIdx.x;
  const int wave = tid >> 6, lane = tid & 63;
  const int m0 = blockIdx.x * 128, n0 = blockIdx.y * 128;
  const int wr = (wave >> 1) * 64, wc = (wave & 1) * 64;
  const int srow = tid >> 2, scol = (tid & 3) * 8;
  const int ka = (lane >> 4) * 8;
  f32x4 acc[4][4];
#pragma unroll
  for (int m = 0; m < 4; ++m)
#pragma unroll
    for (int n = 0; n < 4; ++n) acc[m][n] = f32x4{0.f, 0.f, 0.f, 0.f};

  for (int k0 = 0; k0 < 1024; k0 += 32) {
#pragma unroll
    for (int r = 0; r < 2; ++r) {
      gload_lds16(A + (size_t)(m0 + r * 64 + srow) * 1024 + k0 + scol,
                  (char*)Al + r * 4096 + wave * 1024);
      gload_lds16(Bt + (size_t)(n0 + r * 64 + srow) * 1024 + k0 + scol,
                  (char*)Bl + r * 4096 + wave * 1024);
    }
    __syncthreads();
    bf16x8 af[4], bfr[4];
#pragma unroll
    for (int m = 0; m < 4; ++m)
      af[m] = *(const bf16x8*)&Al[(wr + m * 16 + (lane & 15)) * 32 + ka];
#pragma unroll
    for (int n = 0; n < 4; ++n)
      bfr[n] = *(const bf16x8*)&Bl[(wc + n * 16 + (lane & 15)) * 32 + ka];
#pragma unroll
    for (int m = 0; m < 4; ++m)
#pragma unroll
      for (int n = 0; n < 4; ++n)
        acc[m][n] = __builtin_amdgcn_mfma_f32_16x16x32_bf16(af[m], bfr[n], acc[m][n], 0, 0, 0);
    __syncthreads();
  }

#pragma unroll
  for (int m = 0; m < 4; ++m)
#pragma unroll
    for (int n = 0; n < 4; ++n)
#pragma unroll
      for (int j = 0; j < 4; ++j) {
        int row = m0 + wr + m * 16 + (lane >> 4) * 4 + j;
        int col = n0 + wc + n * 16 + (lane & 15);
        float v = acc[m][n][j] + bias[col];
        int which = col >> 10;
        int h = (col >> 6) & 15;
        int d = col & 63;
        int b = row >> 11, t = row & (T_SEQ - 1);
        int bh = b * NHEAD + h;
        unsigned short bv = f2bf(which == 1 ? v * 0.18033688f : v);
        size_t tb = ((size_t)bh * 32 + (t >> 6)) * 4096;
        if (which == 2) {
          vb[tb + (d >> 5) * 2048 + ((t >> 4) & 3) * 512 + (d & 31) * 16 +
             ((t >> 3) & 1) * 8 + (t & 7)] = bv;
        } else {
          size_t a = tb + ((t >> 5) & 1) * 2048 + (d >> 4) * 512 + (t & 31) * 16 +
                     ((d >> 3) & 1) * 8 + (d & 7);
          if (which == 0) qb[a] = bv; else kb[a] = bv;
        }
      }
}

// GEMM2: out = A[4096][1024] * Bt[1024][1024]^T + bias, fp32 out, direct
// stores (R15's atomic K-split REVERTED: 8.4M scalar fp32 atomics serialized
// at L2 and regressed 19us). 64x128 tile, grid (64,8)=512 blocks=2/CU.
// THIS ROUND: BK=64 -> 16 K-steps (was 32) => half the barrier pairs, 16
// MFMAs/wave/step. LDS stored as [kk][rows][32] (two 32-col half-tiles) so
// every gload_lds pass keeps the proven wave*1024+lane*16 linear destination
// (derivation: dst = kk*half + (tid>>2)*64B + (tid&3)*16B == wave*1024 +
// lane*16) and fragment reads keep the same 64B-row-stride addressing as
// GEMM1 (identical bank profile, no swizzle needed). LDS 24KB.
__global__ __launch_bounds__(256) void k_gemm2(const unsigned short* __restrict__ A,
                                               const unsigned short* __restrict__ Bt,
                                               const float* __restrict__ bias,
                                               float* __restrict__ outF) {
  __shared__ __align__(16) unsigned short Al[2 * 64 * 32];   //  8 KB [kk][64][32]
  __shared__ __align__(16) unsigned short Bl[2 * 128 * 32];  // 16 KB [kk][128][32]
  const int tid = threadIdx.x;
  const int wave = tid >> 6, lane = tid & 63;
  const int m0 = blockIdx.x * 64, n0 = blockIdx.y * 128;
  const int wr = (wave >> 1) * 32, wc = (wave & 1) * 64;
  const int srow = tid >> 2, scol = (tid & 3) * 8;   // 64 rows x 32 cols per pass
  const int ka = (lane >> 4) * 8;
  f32x4 acc[2][4];
#pragma unroll
  for (int m = 0; m < 2; ++m)
#pragma unroll
    for (int n = 0; n < 4; ++n) acc[m][n] = f32x4{0.f, 0.f, 0.f, 0.f};

  for (int k0 = 0; k0 < 1024; k0 += 64) {
#pragma unroll
    for (int kk = 0; kk < 2; ++kk) {
      gload_lds16(A + (size_t)(m0 + srow) * 1024 + k0 + kk * 32 + scol,
                  (char*)Al + kk * 4096 + wave * 1024);
#pragma unroll
      for (int r = 0; r < 2; ++r)
        gload_lds16(Bt + (size_t)(n0 + r * 64 + srow) * 1024 + k0 + kk * 32 + scol,
                    (char*)Bl + kk * 8192 + r * 4096 + wave * 1024);
    }
    __syncthreads();
    bf16x8 af[2][2], bfr[2][4];
#pragma unroll
    for (int kk = 0; kk < 2; ++kk) {
#pragma unroll
      for (int m = 0; m < 2; ++m)
        af[kk][m] = *(const bf16x8*)&Al[kk * 2048 + (wr + m * 16 + (lane & 15)) * 32 + ka];
#pragma unroll
      for (int n = 0; n < 4; ++n)
        bfr[kk][n] = *(const bf16x8*)&Bl[kk * 4096 + (wc + n * 16 + (lane & 15)) * 32 + ka];
    }
#pragma unroll
    for (int kk = 0; kk < 2; ++kk)
#pragma unroll
      for (int m = 0; m < 2; ++m)
#pragma unroll
        for (int n = 0; n < 4; ++n)
          acc[m][n] = __builtin_amdgcn_mfma_f32_16x16x32_bf16(af[kk][m], bfr[kk][n], acc[m][n], 0, 0, 0);
    __syncthreads();
  }

#pragma unroll
  for (int m = 0; m < 2; ++m)
#pragma unroll
    for (int n = 0; n < 4; ++n)
#pragma unroll
      for (int j = 0; j < 4; ++j) {
        int row = m0 + wr + m * 16 + (lane >> 4) * 4 + j;
        int col = n0 + wc + n * 16 + (lane & 15);
        outF[(size_t)row * CDIM + col] = acc[m][n][j] + bias[col];
      }
}

// Flash attention: R14 structure (KV-split-4, 32x32 lane-local softmax,
// pipelined QK, permlane reduces, defer-max, fragment-linear Q/K/V, balanced
// pairs, 4-way LDS merge twice per block). R15's out-zeroing removed.
#define MOSTR 67
__global__ __launch_bounds__(256) void k_attn(const unsigned short* __restrict__ qb,
                                              const unsigned short* __restrict__ kb,
                                              const unsigned short* __restrict__ vb,
                                              unsigned short* __restrict__ yb) {
  __shared__ float Mo[4 * 32 * MOSTR];   // 34304 B partial O^T
  __shared__ float Lml[4][2][32];        // partial m, l per q
  // rid -> (xcd, bh, pair). 8 XCDs x 4 bh x 32 pairs = 1024 blocks.
  const int rid = blockIdx.x;
  const int xcd = rid & 7, i = rid >> 3;       // i in 0..127
  const int bh = xcd * 4 + (i & 3);
  const int p = i >> 2;                        // 0..31
  const int wave = threadIdx.x >> 6;           // 0..3
  const int lane = threadIdx.x & 63;
  const int l31 = lane & 31, hi = lane >> 5;
  const unsigned short* qh = qb + (size_t)bh * T_SEQ * HS;
  const unsigned short* kh = kb + (size_t)bh * T_SEQ * HS;
  const unsigned short* vh = vb + (size_t)bh * T_SEQ * HS;
  const int b = bh >> 4, h = bh & 15;
  const int lbase = l31 * 16 + hi * 8;         // per-lane offset within a 512-slab

  for (int grp = 0; grp < 2; ++grp) {
    const int g = grp ? p : 63 - p;
    const int q0 = g * 32;
    const int nkt = (q0 >> 6) + 1;

    // Q B-frags (fragment-linear): col=q=l31, k(d) = dd*16 + hi*8 + {0..7}
    const size_t qbase = (size_t)(g >> 1) * 4096 + (size_t)(g & 1) * 2048;
    bf16x8 qf[4];
#pragma unroll
    for (int dd = 0; dd < 4; ++dd)
      qf[dd] = *(const bf16x8*)&qh[qbase + dd * 512 + lbase];

    f32x16 o2[2];                 // O^T acc: col=q=l31, rows d = db*32 + rowpat
#pragma unroll
    for (int db = 0; db < 2; ++db)
#pragma unroll
      for (int e = 0; e < 16; ++e) o2[db][e] = 0.f;
    float Mx = -INFINITY, Ls = 0.f;

    // prologue: K A-frags + QK of this wave's first tile (index < 32, in-bounds)
    bf16x8 kf[2][4];
#pragma unroll
    for (int kbk = 0; kbk < 2; ++kbk)
#pragma unroll
      for (int dd = 0; dd < 4; ++dd)
        kf[kbk][dd] = *(const bf16x8*)&kh[(size_t)wave * 4096 + kbk * 2048 + dd * 512 + lbase];
    f32x16 s[2];
#pragma unroll
    for (int kbk = 0; kbk < 2; ++kbk) {
      f32x16 z;
#pragma unroll
      for (int e = 0; e < 16; ++e) z[e] = 0.f;
#pragma unroll
      for (int dd = 0; dd < 4; ++dd)
        z = __builtin_amdgcn_mfma_f32_32x32x16_bf16(kf[kbk][dd], qf[dd], z, 0, 0, 0);
      s[kbk] = z;
    }

    for (int kt = wave; kt < nkt; kt += 4) {
      const int kvb = kt * 64;
      const bool more = (kt + 4 < nkt);

      // issue K loads for tile kt+4 (kf regs free: QK(kt) already computed)
      if (more) {
#pragma unroll
        for (int kbk = 0; kbk < 2; ++kbk)
#pragma unroll
          for (int dd = 0; dd < 4; ++dd)
            kf[kbk][dd] = *(const bf16x8*)&kh[(size_t)(kt + 4) * 4096 + kbk * 2048 + dd * 512 + lbase];
      }
      // issue V loads for THIS tile (consumed after softmax -> latency hidden)
      bf16x8 vf[2][4];
#pragma unroll
      for (int db = 0; db < 2; ++db)
#pragma unroll
        for (int t16 = 0; t16 < 4; ++t16)
          vf[db][t16] = *(const bf16x8*)&vh[(size_t)kt * 4096 + db * 2048 + t16 * 512 + lbase];

      // causal mask (only the group's last tile has kvb+63 > q0)
      if (kvb + 63 > q0) {
        const int qg = q0 + l31;
#pragma unroll
        for (int kbk = 0; kbk < 2; ++kbk)
#pragma unroll
          for (int r = 0; r < 16; ++r) {
            const int key = kvb + kbk * 32 + (r & 3) + 8 * (r >> 2) + 4 * hi;
            if (key > qg) s[kbk][r] = -3.0e38f;
          }
      }

      // row max: in-register tree (31 fmax) + permlane cross-half
      f32x16 tm;
#pragma unroll
      for (int e = 0; e < 16; ++e) tm[e] = fmaxf(s[0][e], s[1][e]);
      float m8[8];
#pragma unroll
      for (int e = 0; e < 8; ++e) m8[e] = fmaxf(tm[e], tm[e + 8]);
      float m4a = fmaxf(m8[0], m8[4]), m4b = fmaxf(m8[1], m8[5]);
      float m4c = fmaxf(m8[2], m8[6]), m4d = fmaxf(m8[3], m8[7]);
      float mx = fmaxf(fmaxf(m4a, m4b), fmaxf(m4c, m4d));
      mx = fmaxf(mx, xhalf_other(mx, hi));

      // defer-max (T13): skip rescale while max growth <= 8 (P <= 2^8).
      if (!__all(mx <= Mx + 8.f)) {
        const float newM = fmaxf(Mx, mx);
        const float alpha = __builtin_exp2f(Mx - newM);
        Mx = newM;
        Ls *= alpha;
#pragma unroll
        for (int db = 0; db < 2; ++db)
#pragma unroll
          for (int e = 0; e < 16; ++e) o2[db][e] *= alpha;
      }

      // p = exp2(s - Mx) in place; row sum (31 adds) + permlane cross-half
#pragma unroll
      for (int kbk = 0; kbk < 2; ++kbk)
#pragma unroll
        for (int r = 0; r < 16; ++r) s[kbk][r] = __builtin_exp2f(s[kbk][r] - Mx);
      f32x16 ts;
#pragma unroll
      for (int e = 0; e < 16; ++e) ts[e] = s[0][e] + s[1][e];
      float s8[8];
#pragma unroll
      for (int e = 0; e < 8; ++e) s8[e] = ts[e] + ts[e + 8];
      float rs = ((s8[0] + s8[1]) + (s8[2] + s8[3])) + ((s8[4] + s8[5]) + (s8[6] + s8[7]));
      rs += xhalf_other(rs, hi);
      Ls += rs;

      // pack P: W[kb][rg] = 2 words (4 bf16, rows 8rg+4hi+{0..3})
      unsigned W0[2][4], W1[2][4];
#pragma unroll
      for (int kbk = 0; kbk < 2; ++kbk)
#pragma unroll
        for (int rg = 0; rg < 4; ++rg) {
          unsigned lo, hiw;
          asm("v_cvt_pk_bf16_f32 %0, %1, %2" : "=v"(lo) : "v"(s[kbk][4 * rg + 0]), "v"(s[kbk][4 * rg + 1]));
          asm("v_cvt_pk_bf16_f32 %0, %1, %2" : "=v"(hiw) : "v"(s[kbk][4 * rg + 2]), "v"(s[kbk][4 * rg + 3]));
          W0[kbk][rg] = lo; W1[kbk][rg] = hiw;
        }

      // build PV B-frags (P^T: col=q=l31, k = t16*16 + hi*8 + {0..7}) with
      // 8 permlane32_swap: swap(W[rgA].w, W[rgB].w) -> both frag halves.
      bf16x8 pf[4];
#pragma unroll
      for (int t16 = 0; t16 < 4; ++t16) {
        const int kbk = t16 >> 1, par = t16 & 1;
        unsigned a0 = W0[kbk][2 * par], b0 = W0[kbk][2 * par + 1];
        unsigned a1 = W1[kbk][2 * par], b1 = W1[kbk][2 * par + 1];
        auto r0 = __builtin_amdgcn_permlane32_swap(a0, b0, false, false);
        auto r1 = __builtin_amdgcn_permlane32_swap(a1, b1, false, false);
        union { unsigned u[4]; bf16x8 v; } cv;
        cv.u[0] = (unsigned)r0[0]; cv.u[1] = (unsigned)r1[0];
        cv.u[2] = (unsigned)r0[1]; cv.u[3] = (unsigned)r1[1];
        pf[t16] = cv.v;
      }

      // PV: O^T[d][q] += V[d][k] * P^T[k][q]
#pragma unroll
      for (int db = 0; db < 2; ++db)
#pragma unroll
        for (int t16 = 0; t16 < 4; ++t16)
          o2[db] = __builtin_amdgcn_mfma_f32_32x32x16_bf16(vf[db][t16], pf[t16], o2[db], 0, 0, 0);

      // QK for tile kt+4 at iteration END (kf loads had softmax+PV to land).
      if (more) {
#pragma unroll
        for (int kbk = 0; kbk < 2; ++kbk) {
          f32x16 z;
#pragma unroll
          for (int e = 0; e < 16; ++e) z[e] = 0.f;
#pragma unroll
          for (int dd = 0; dd < 4; ++dd)
            z = __builtin_amdgcn_mfma_f32_32x32x16_bf16(kf[kbk][dd], qf[dd], z, 0, 0, 0);
          s[kbk] = z;
        }
      }
    }

    // ---- publish partials ----
    if (hi == 0) {
      Lml[wave][0][l31] = Mx;
      Lml[wave][1][l31] = Ls;
    }
#pragma unroll
    for (int db = 0; db < 2; ++db)
#pragma unroll
      for (int r = 0; r < 16; ++r)
        Mo[wave * 32 * MOSTR + l31 * MOSTR + db * 32 + (r & 3) + 8 * (r >> 2) + 4 * hi] = o2[db][r];
    __syncthreads();

    // ---- distributed 4-way merge + store: 256 chunks of 8 cols ----
    {
      const int c = threadIdx.x;
      const int rl = c >> 3, c0 = (c & 7) * 8;
      const float m0 = Lml[0][0][rl], m1 = Lml[1][0][rl], m2 = Lml[2][0][rl], m3 = Lml[3][0][rl];
      const float l0 = Lml[0][1][rl], l1 = Lml[1][1][rl], l2 = Lml[2][1][rl], l3 = Lml[3][1][rl];
      const float M = fmaxf(fmaxf(m0, m1), fmaxf(m2, m3));
      const float a0 = __builtin_exp2f(m0 - M);
      const float a1 = __builtin_exp2f(m1 - M);
      const float a2 = __builtin_exp2f(m2 - M);
      const float a3 = __builtin_exp2f(m3 - M);
      const float inv = 1.0f / (a0 * l0 + a1 * l1 + a2 * l2 + a3 * l3);
      const float* O0 = &Mo[rl * MOSTR + c0];
      const float* O1 = O0 + 32 * MOSTR;
      const float* O2 = O0 + 64 * MOSTR;
      const float* O3 = O0 + 96 * MOSTR;
      unsigned pk[4];
#pragma unroll
      for (int e = 0; e < 4; ++e) {
        float va = (a0 * O0[2 * e] + a1 * O1[2 * e] + a2 * O2[2 * e] + a3 * O3[2 * e]) * inv;
        float vb2 = (a0 * O0[2 * e + 1] + a1 * O1[2 * e + 1] + a2 * O2[2 * e + 1] + a3 * O3[2 * e + 1]) * inv;
        pk[e] = (unsigned)f2bf(va) | ((unsigned)f2bf(vb2) << 16);
      }
      uint4 u; u.x = pk[0]; u.y = pk[1]; u.z = pk[2]; u.w = pk[3];
      *(uint4*)&yb[(size_t)(b * T_SEQ + q0 + rl) * CDIM + h * 64 + c0] = u;
    }
    __syncthreads();  // Mo reused by next group
  }
}

extern "C" void kernel_launch(void* const* d_in, const int* in_sizes, int n_in,
                              void* d_out, int out_size, void* d_ws, size_t ws_size,
                              hipStream_t stream) {
  (void)in_sizes; (void)n_in; (void)out_size; (void)ws_size;
  const float* x      = (const float*)d_in[0];
  const float* W_attn = (const float*)d_in[1];
  const float* b_attn = (const float*)d_in[2];
  const float* W_proj = (const float*)d_in[3];
  const float* b_proj = (const float*)d_in[4];
  float* out = (float*)d_out;
  char* ws = (char*)d_ws;

  unsigned short* xb  = (unsigned short*)(ws);              //  8 MiB [4096][1024]
  unsigned short* Wta = (unsigned short*)(ws + 8388608);    //  6 MiB [3072][1024]
  unsigned short* Wtp = (unsigned short*)(ws + 14680064);   //  2 MiB [1024][1024]
  unsigned short* qbf = (unsigned short*)(ws + 16777216);   //  8 MiB fragment-linear
  unsigned short* kbf = (unsigned short*)(ws + 25165824);   //  8 MiB fragment-linear
  unsigned short* vbf = (unsigned short*)(ws + 33554432);   //  8 MiB fragment-linear
  unsigned short* ybf = (unsigned short*)(ws + 41943040);   //  8 MiB [4096][1024]

  k_prep<<<8192, 256, 0, stream>>>(x, xb, W_attn, Wta, W_proj, Wtp);
  k_gemm1<<<dim3(32, 24), 256, 0, stream>>>(xb, Wta, b_attn, qbf, kbf, vbf);
  k_attn<<<1024, 256, 0, stream>>>(qbf, kbf, vbf, ybf);
  k_gemm2<<<dim3(64, 8), 256, 0, stream>>>(ybf, Wtp, b_proj, out);
}